// Round 3
// baseline (511.022 us; speedup 1.0000x reference)
//
#include <hip/hip_runtime.h>

// LengthRegulator: B=32, T=1024, D=384, MAXLEN=8192 (fixed by harness).
// v7 = MEASUREMENT PROBE. Kernel code is byte-identical to v4 (best-known,
// 437 us): frame-centric expand, 1 frame per 192-thread block, fused tail
// fill. The ONLY change: lr_expand4 is launched TWICE (idempotent -> output
// identical, passes). Same-stream serialization makes
//   dur_us(v7) - dur_us(v4)  =  T_expand
// which top-5-only rocprof cannot show (expand < 250 us fills). This
// resolves whether expand is ~175 us (100 us headroom -> keep attacking)
// or ~70 us (at the 402 MB / 6.3 TB/s write floor -> declare ceiling).

#define B_    32
#define T_    1024
#define D_    384
#define ML_   8192
#define D4_   (D_ / 4)     // 96 float4 per row
#define NTHR  192          // 2 rows per window, exactly 3 waves
#define NFILL 32           // fill-role blocks per batch

// --- Kernel 1: per-batch inclusive scan of clamped durations -------------
__global__ __launch_bounds__(T_) void lr_scan(const int* __restrict__ dur,
                                              int* __restrict__ cum,
                                              float* __restrict__ total_out) {
    const int b = blockIdx.x;
    const int t = threadIdx.x;
    const int lane = t & 63;
    const int wave = t >> 6;

    int v = dur[b * T_ + t];
    v = v > 0 ? v : 0;

    for (int off = 1; off < 64; off <<= 1) {
        int n = __shfl_up(v, off, 64);
        if (lane >= off) v += n;
    }

    __shared__ int wsum[16];
    if (lane == 63) wsum[wave] = v;
    __syncthreads();

    if (wave == 0 && lane < 16) {
        int w = wsum[lane];
        for (int off = 1; off < 16; off <<= 1) {
            int n = __shfl_up(w, off, 64);
            if (lane >= off) w += n;
        }
        wsum[lane] = w;
    }
    __syncthreads();

    int c = v + (wave > 0 ? wsum[wave - 1] : 0);
    cum[b * T_ + t] = c;
    if (t == T_ - 1) {
        total_out[b] = (float)c;   // total <= 15360, exact in fp32
    }
}

// --- Kernel 2: expand + tail-fill (IDENTICAL to v4) -----------------------
// grid = (T_ + NFILL, B_), 192 threads. bi < T_: expand frame bi; else fill.
__global__ __launch_bounds__(NTHR) void lr_expand4(const float4* __restrict__ x,
                                                   const int* __restrict__ cum,
                                                   float4* __restrict__ out) {
    const int b  = blockIdx.y;
    const int bi = blockIdx.x;
    const int t  = threadIdx.x;
    const int* cb = cum + b * T_;

    if (bi < T_) {
        // ---- expand role: frame bi owns output rows [cum[bi-1], cum[bi]) --
        int end   = cb[bi];                       // wave-uniform scalar load
        int start = bi ? cb[bi - 1] : 0;          // wave-uniform scalar load
        if (end > ML_) end = ML_;                 // total may exceed MAXLEN
        if (start >= end) return;                 // dur==0 or fully clipped

        const int col = (t >= D4_) ? t - D4_ : t; // 0..95, lane's column
        const float4 v = x[((size_t)b * T_ + bi) * D4_ + col];
        float4* ob = out + (size_t)b * ML_ * D4_;

        // 2-row windows: t in [0,192) spans rows r (t<96) and r+1 (t>=96),
        // identical content -> each wave stores 1 KB contiguous per iter.
        int r = start;
        for (; r + 1 < end; r += 2)
            ob[(size_t)r * D4_ + t] = v;
        if (r < end && t < D4_)                   // odd-count tail row
            ob[(size_t)r * D4_ + t] = v;
    } else {
        // ---- fill role: zero rows [min(total,ML), ML), contiguous slices --
        const int fb    = bi - T_;                // 0..NFILL-1
        const int total = cb[T_ - 1];
        const int tr    = total < ML_ ? total : ML_;
        const int n     = (ML_ - tr) * D4_;       // float4 count to zero
        const int per   = (n + NFILL - 1) / NFILL;
        const int off   = fb * per;
        int cnt = n - off;
        if (cnt > per) cnt = per;
        if (cnt <= 0) return;
        float4* o = out + ((size_t)b * ML_ + tr) * D4_ + off;
        const float4 z = make_float4(0.f, 0.f, 0.f, 0.f);
        for (int j = t; j < cnt; j += NTHR)
            o[j] = z;
    }
}

extern "C" void kernel_launch(void* const* d_in, const int* in_sizes, int n_in,
                              void* d_out, int out_size, void* d_ws, size_t ws_size,
                              hipStream_t stream) {
    const float* x   = (const float*)d_in[0];   // (B, T, D) fp32
    const int*   dur = (const int*)d_in[1];     // (B, T) int32
    // d_in[2] = max_len scalar (always 8192 here)

    float* out       = (float*)d_out;                   // (B, ML, D) fp32
    float* total_out = out + (size_t)B_ * ML_ * D_;     // (B,) as fp32
    int*   cum       = (int*)d_ws;                      // (B, T) scratch

    lr_scan<<<B_, T_, 0, stream>>>(dur, cum, total_out);
    // PROBE: expand launched twice (idempotent). dur_us delta vs v4 == T_expand.
    lr_expand4<<<dim3(T_ + NFILL, B_), NTHR, 0, stream>>>(
        (const float4*)x, cum, (float4*)out);
    lr_expand4<<<dim3(T_ + NFILL, B_), NTHR, 0, stream>>>(
        (const float4*)x, cum, (float4*)out);
}

// Round 4
// 435.175 us; speedup vs baseline: 1.1743x; 1.1743x over previous
//
#include <hip/hip_runtime.h>

// LengthRegulator: B=32, T=1024, D=384, MAXLEN=8192 (fixed by harness).
// v8 = v4 restored (best-known, 437 us). Frame-centric expand: one frame per
// 192-thread block (3 waves, 100% lanes); a frame's dur copies are
// CONSECUTIVE IDENTICAL rows, so lanes cover a 2-row window (192 float4 =
// 3 KB) and every wave store is one contiguous 1 KB transaction. cum read
// via 2 wave-uniform scalar loads -- no LDS, no barrier. Tail zero-fill
// fused as 32 contiguous-slice fill blocks per batch.
//
// CEILING (measured, r3 double-launch probe): T_expand = 511.0-437.3 = 74 us
// vs 453 MB (402.7 MB stores + 50.3 MB reads) / 6.33 TB/s = 71.6 us floor
// (6.33 TB/s = the harness fill's own measured BW on this buffer) -> 97% of
// the memory roofline. Remaining dur_us is harness poison fill (~253 us) +
// reset dispatches (~105 us) + scan (~5 us), outside kernel control.

#define B_    32
#define T_    1024
#define D_    384
#define ML_   8192
#define D4_   (D_ / 4)     // 96 float4 per row
#define NTHR  192          // 2 rows per window, exactly 3 waves
#define NFILL 32           // fill-role blocks per batch

// --- Kernel 1: per-batch inclusive scan of clamped durations -------------
__global__ __launch_bounds__(T_) void lr_scan(const int* __restrict__ dur,
                                              int* __restrict__ cum,
                                              float* __restrict__ total_out) {
    const int b = blockIdx.x;
    const int t = threadIdx.x;
    const int lane = t & 63;
    const int wave = t >> 6;

    int v = dur[b * T_ + t];
    v = v > 0 ? v : 0;

    for (int off = 1; off < 64; off <<= 1) {
        int n = __shfl_up(v, off, 64);
        if (lane >= off) v += n;
    }

    __shared__ int wsum[16];
    if (lane == 63) wsum[wave] = v;
    __syncthreads();

    if (wave == 0 && lane < 16) {
        int w = wsum[lane];
        for (int off = 1; off < 16; off <<= 1) {
            int n = __shfl_up(w, off, 64);
            if (lane >= off) w += n;
        }
        wsum[lane] = w;
    }
    __syncthreads();

    int c = v + (wave > 0 ? wsum[wave - 1] : 0);
    cum[b * T_ + t] = c;
    if (t == T_ - 1) {
        total_out[b] = (float)c;   // total <= 15360, exact in fp32
    }
}

// --- Kernel 2: expand + tail-fill ----------------------------------------
// grid = (T_ + NFILL, B_), 192 threads. bi < T_: expand frame bi; else fill.
__global__ __launch_bounds__(NTHR) void lr_expand4(const float4* __restrict__ x,
                                                   const int* __restrict__ cum,
                                                   float4* __restrict__ out) {
    const int b  = blockIdx.y;
    const int bi = blockIdx.x;
    const int t  = threadIdx.x;
    const int* cb = cum + b * T_;

    if (bi < T_) {
        // ---- expand role: frame bi owns output rows [cum[bi-1], cum[bi]) --
        int end   = cb[bi];                       // wave-uniform scalar load
        int start = bi ? cb[bi - 1] : 0;          // wave-uniform scalar load
        if (end > ML_) end = ML_;                 // total may exceed MAXLEN
        if (start >= end) return;                 // dur==0 or fully clipped

        const int col = (t >= D4_) ? t - D4_ : t; // 0..95, lane's column
        const float4 v = x[((size_t)b * T_ + bi) * D4_ + col];
        float4* ob = out + (size_t)b * ML_ * D4_;

        // 2-row windows: t in [0,192) spans rows r (t<96) and r+1 (t>=96),
        // identical content -> each wave stores 1 KB contiguous per iter.
        int r = start;
        for (; r + 1 < end; r += 2)
            ob[(size_t)r * D4_ + t] = v;
        if (r < end && t < D4_)                   // odd-count tail row
            ob[(size_t)r * D4_ + t] = v;
    } else {
        // ---- fill role: zero rows [min(total,ML), ML), contiguous slices --
        const int fb    = bi - T_;                // 0..NFILL-1
        const int total = cb[T_ - 1];
        const int tr    = total < ML_ ? total : ML_;
        const int n     = (ML_ - tr) * D4_;       // float4 count to zero
        const int per   = (n + NFILL - 1) / NFILL;
        const int off   = fb * per;
        int cnt = n - off;
        if (cnt > per) cnt = per;
        if (cnt <= 0) return;
        float4* o = out + ((size_t)b * ML_ + tr) * D4_ + off;
        const float4 z = make_float4(0.f, 0.f, 0.f, 0.f);
        for (int j = t; j < cnt; j += NTHR)
            o[j] = z;
    }
}

extern "C" void kernel_launch(void* const* d_in, const int* in_sizes, int n_in,
                              void* d_out, int out_size, void* d_ws, size_t ws_size,
                              hipStream_t stream) {
    const float* x   = (const float*)d_in[0];   // (B, T, D) fp32
    const int*   dur = (const int*)d_in[1];     // (B, T) int32
    // d_in[2] = max_len scalar (always 8192 here)

    float* out       = (float*)d_out;                   // (B, ML, D) fp32
    float* total_out = out + (size_t)B_ * ML_ * D_;     // (B,) as fp32
    int*   cum       = (int*)d_ws;                      // (B, T) scratch

    lr_scan<<<B_, T_, 0, stream>>>(dur, cum, total_out);
    lr_expand4<<<dim3(T_ + NFILL, B_), NTHR, 0, stream>>>(
        (const float4*)x, cum, (float4*)out);
}